// Round 4
// baseline (408.134 us; speedup 1.0000x reference)
//
#include <hip/hip_runtime.h>
#include <cstdint>
#include <cstddef>

// DeformConv2d B=8 C=256 H=W=64 Cout=256 K=3 s=1 p=1 d=1
// Prepass: weight fp32 -> bf16 into d_ws (1.18 MB, L2-resident).
// Main: fused bilinear im2col (bf16 LDS cols per 32-ch chunk) + MFMA GEMM.
// Grid = (b, ho) = 512 blocks x 512 thr (8 waves). Block tile 256co x 64px.
// Bilinear tables held in REGISTERS per thread (px = lane): 9 taps x
// {offA, offB byte offsets; wA, wB x-selection-folded f32x2 weights}.
// Corner pairs loaded as <2 x float> align-4 (x1 = x0+1 contiguous).
// K ordering: k = c*9 + kk (matches weight [co][c][kk] flat layout).

#define B_   8
#define C_   256
#define H_   64
#define W_   64
#define CO_  256
#define KK_  9
#define CC   32              // channels per chunk
#define PADK 296             // padded k row (bf16): 592B rows, 16B-aligned

typedef short  short4_t __attribute__((ext_vector_type(4)));
typedef short  short8   __attribute__((ext_vector_type(8)));
typedef float  f32x4    __attribute__((ext_vector_type(4)));
typedef float  f32x2    __attribute__((ext_vector_type(2)));

__device__ inline short f2bf(float f) {   // round-to-nearest-even fp32->bf16
    uint32_t u = __builtin_bit_cast(uint32_t, f);
    u += 0x7FFFu + ((u >> 16) & 1u);
    return (short)(u >> 16);
}

// ---- prepass: weight fp32 -> bf16 ----
__global__ __launch_bounds__(256) void w2bf(const float* __restrict__ w,
                                            short* __restrict__ wb, int n8) {
    const int i = blockIdx.x * 256 + threadIdx.x;
    if (i >= n8) return;
    const f32x4 a = *reinterpret_cast<const f32x4*>(w + i * 8);
    const f32x4 b = *reinterpret_cast<const f32x4*>(w + i * 8 + 4);
    short8 v;
#pragma unroll
    for (int j = 0; j < 4; ++j) { v[j] = f2bf(a[j]); v[j + 4] = f2bf(b[j]); }
    *reinterpret_cast<short8*>(wb + i * 8) = v;
}

__global__ __launch_bounds__(512, 4) void dcn_mfma(
    const float* __restrict__ x,
    const float* __restrict__ offset,
    const short* __restrict__ wbf,     // bf16 weight [256][2304]
    const float* __restrict__ bias,
    float* __restrict__ out)
{
    __shared__ short cols[64 * PADK];   // [px][k] bf16 columns, one chunk

    const int bid = blockIdx.x;         // 512 = 64 * 8
    const int ho  = bid & 63;
    const int b   = bid >> 6;

    const int t    = threadIdx.x;
    const int lane = t & 63;
    const int wave = t >> 6;

    // ---- per-thread bilinear tables for px = lane (registers) ----
    uint32_t offA[KK_], offB[KK_];
    f32x2    wA[KK_],  wB[KK_];
    {
        const int wo = lane;
#pragma unroll
        for (int kk = 0; kk < KK_; ++kk) {
            const int ky = kk / 3, kx = kk % 3;
            const float offy = offset[(((b * 18) + kk * 2 + 0) * 64 + ho) * 64 + wo];
            const float offx = offset[(((b * 18) + kk * 2 + 1) * 64 + ho) * 64 + wo];
            const float py  = (float)(ho - 1 + ky) + offy;
            const float pxx = (float)(wo - 1 + kx) + offx;
            const float y0f = floorf(py), x0f = floorf(pxx);
            const float wy = py - y0f, wx = pxx - x0f;
            const int y0 = (int)y0f, x0 = (int)x0f;
            const int y1 = y0 + 1,   x1 = x0 + 1;
            const float vy0 = (y0 >= 0 && y0 < H_) ? 1.f : 0.f;
            const float vy1 = (y1 >= 0 && y1 < H_) ? 1.f : 0.f;
            const float vx0 = (x0 >= 0 && x0 < W_) ? 1.f : 0.f;
            const float vx1 = (x1 >= 0 && x1 < W_) ? 1.f : 0.f;
            const float wv0 = (1.f - wy) * (1.f - wx) * vy0 * vx0;
            const float wv1 = (1.f - wy) * wx         * vy0 * vx1;
            const float wv2 = wy         * (1.f - wx) * vy1 * vx0;
            const float wv3 = wy         * wx         * vy1 * vx1;
            const int y0c = min(max(y0, 0), H_ - 1);
            const int y1c = min(max(y1, 0), H_ - 1);
            const int x0c = min(max(x0, 0), W_ - 1);
            const int x1c = min(max(x1, 0), W_ - 1);
            const int xb0 = min(max(x0, 0), W_ - 2);   // pair base (x covers xb0, xb0+1)
            // fold x-slot selection into the weights
            const float sA0 = (x0c == xb0)     ? 1.f : 0.f;
            const float sB0 = (x1c == xb0)     ? 1.f : 0.f;
            const float sA1 = (x0c == xb0 + 1) ? 1.f : 0.f;
            const float sB1 = (x1c == xb0 + 1) ? 1.f : 0.f;
            f32x2 a, bb;
            a[0]  = sA0 * wv0 + sB0 * wv1;
            a[1]  = sA1 * wv0 + sB1 * wv1;
            bb[0] = sA0 * wv2 + sB0 * wv3;
            bb[1] = sA1 * wv2 + sB1 * wv3;
            wA[kk] = a; wB[kk] = bb;
            offA[kk] = (uint32_t)(y0c * W_ + xb0) * 4u;
            offB[kk] = (uint32_t)(y1c * W_ + xb0) * 4u;
        }
    }

    f32x4 acc[4][2];   // [mt co][nt px]
#pragma unroll
    for (int i = 0; i < 4; ++i) { acc[i][0] = (f32x4)0.f; acc[i][1] = (f32x4)0.f; }

    const int wm = wave >> 1;          // co-64 group
    const int wn = wave & 1;           // px-32 group
    const int co0 = __builtin_amdgcn_readfirstlane(wm * 64);
    const int px0 = __builtin_amdgcn_readfirstlane(wn * 32);
    const int m_l = lane & 15;         // row/col index within 16x16 fragment
    const int k_l = (lane >> 4) << 3;  // 8 contiguous k per lane

    // weight row bases (per thread, fixed across chunks)
    const short* wrow[4];
#pragma unroll
    for (int mt = 0; mt < 4; ++mt)
        wrow[mt] = wbf + (size_t)(co0 + mt * 16 + m_l) * (C_ * KK_);

    for (int c0 = 0; c0 < C_; c0 += CC) {
        // ---- stage bf16 columns: thread covers px=lane, channels 4*wave..+3 ----
        const char* xb[4];
#pragma unroll
        for (int dc = 0; dc < 4; ++dc)
            xb[dc] = (const char*)(x + ((size_t)(b * C_ + c0 + 4 * wave + dc) << 12));

#pragma unroll
        for (int j = 0; j < 9; ++j) {
            short4_t vs;
#pragma unroll
            for (int jj = 0; jj < 4; ++jj) {
                const int idx = j * 4 + jj;      // 0..35 (static)
                const int dc  = idx / 9;         // static
                const int kk  = idx % 9;         // static
                f32x2 lo, hi;
                __builtin_memcpy(&lo, xb[dc] + offA[kk], 8);
                __builtin_memcpy(&hi, xb[dc] + offB[kk], 8);
                const float v = wA[kk][0] * lo[0] + wA[kk][1] * lo[1]
                              + wB[kk][0] * hi[0] + wB[kk][1] * hi[1];
                vs[jj] = f2bf(v);
            }
            *reinterpret_cast<short4_t*>(&cols[lane * PADK + (wave * 9 + j) * 4]) = vs;
        }
        __syncthreads();

        // ---- MFMA over 9 k-steps ----
#pragma unroll
        for (int s = 0; s < 9; ++s) {
            const int krow = s * 32 + k_l;
            short8 bf[2];
#pragma unroll
            for (int nt = 0; nt < 2; ++nt)
                bf[nt] = *reinterpret_cast<const short8*>(
                    &cols[(px0 + nt * 16 + m_l) * PADK + krow]);
            const int kglob = c0 * 9 + krow;
#pragma unroll
            for (int mt = 0; mt < 4; ++mt) {
                const short8 af = *reinterpret_cast<const short8*>(wrow[mt] + kglob);
#pragma unroll
                for (int nt = 0; nt < 2; ++nt)
                    acc[mt][nt] = __builtin_amdgcn_mfma_f32_16x16x32_bf16(
                        af, bf[nt], acc[mt][nt], 0, 0, 0);
            }
        }
        __syncthreads();
    }

    // ---- epilogue: D mapping col=lane&15 (n=px), row=(lane>>4)*4+r (m=co) ----
    const int r0 = (lane >> 4) << 2;
#pragma unroll
    for (int mt = 0; mt < 4; ++mt) {
#pragma unroll
        for (int r = 0; r < 4; ++r) {
            const int co = co0 + mt * 16 + r0 + r;
            const float bv = bias[co];
            float* orow = out + ((size_t)(b * CO_ + co) * H_ + ho) * W_;
#pragma unroll
            for (int nt = 0; nt < 2; ++nt) {
                const int wo = px0 + nt * 16 + m_l;
                orow[wo] = acc[mt][nt][r] + bv;
            }
        }
    }
}

extern "C" void kernel_launch(void* const* d_in, const int* in_sizes, int n_in,
                              void* d_out, int out_size, void* d_ws, size_t ws_size,
                              hipStream_t stream) {
    const float* x      = (const float*)d_in[0];
    const float* offset = (const float*)d_in[1];
    const float* weight = (const float*)d_in[2];
    const float* bias   = (const float*)d_in[3];
    float* out = (float*)d_out;
    short* wbf = (short*)d_ws;          // 589824 bf16 = 1.18 MB
    (void)in_sizes; (void)n_in; (void)out_size; (void)ws_size;

    const int n8 = (CO_ * C_ * KK_) / 8;        // 73728 short8 groups
    hipLaunchKernelGGL(w2bf, dim3((n8 + 255) / 256), dim3(256), 0, stream,
                       weight, wbf, n8);
    hipLaunchKernelGGL(dcn_mfma, dim3(64 * B_), dim3(512), 0, stream,
                       x, offset, wbf, bias, out);
}